// Round 7
// baseline (363.299 us; speedup 1.0000x reference)
//
#include <hip/hip_runtime.h>

// Problem constants: B=2, L=2048, D=2048, H=16, DH=128
#define SEQL 2048
#define NHEAD 16
#define N3 6144      // 3*D
#define KDIM 2048    // D

typedef __attribute__((ext_vector_type(8))) short bf16x8;
typedef __attribute__((ext_vector_type(4))) float f32x4;
typedef __attribute__((ext_vector_type(16))) float f32x16;
typedef __attribute__((ext_vector_type(4))) unsigned short us4;
typedef __attribute__((ext_vector_type(4))) float fl4;
typedef __attribute__((ext_vector_type(4))) unsigned int u32x4;

__device__ __forceinline__ unsigned short f2bf(float x) {
    unsigned u = __builtin_bit_cast(unsigned, x);
    u += 0x7fffu + ((u >> 16) & 1u);            // RNE (inputs are finite)
    return (unsigned short)(u >> 16);
}

__device__ __forceinline__ void gload16(const void* g, void* l) {
    __builtin_amdgcn_global_load_lds(
        (const __attribute__((address_space(1))) unsigned int*)g,
        (__attribute__((address_space(3))) unsigned int*)l,
        16, 0, 0);
}

__device__ __forceinline__ unsigned cvtpk_bf16(float lo, float hi) {
    unsigned r;
    asm("v_cvt_pk_bf16_f32 %0, %1, %2" : "=v"(r) : "v"(lo), "v"(hi));
    return r;
}
__device__ __forceinline__ void plane32_swap(unsigned &a, unsigned &b) {
    asm("v_permlane32_swap_b32 %0, %1" : "+v"(a), "+v"(b));
}

// ---------------- Fused prep: X fp32->bf16  +  W [K][N]->Wt [N][K] bf16 ------
__global__ __launch_bounds__(256) void k_prep(const float* __restrict__ X,
                                              const float* __restrict__ W,
                                              unsigned short* __restrict__ Xb,
                                              unsigned short* __restrict__ Wt) {
    __shared__ alignas(16) unsigned short Ts[64 * 68];
    int bid = blockIdx.x, t = threadIdx.x;
    if (bid < 2048) {                            // ---- convert X ----
        int tid = bid * 256 + t;
        const fl4* in4 = (const fl4*)X;
        us4* out4 = (us4*)Xb;
#pragma unroll
        for (int j = 0; j < 4; ++j) {
            int idx = tid + j * 524288;
            fl4 v = in4[idx];
            us4 o;
            o.x = f2bf(v.x); o.y = f2bf(v.y); o.z = f2bf(v.z); o.w = f2bf(v.w);
            out4[idx] = o;
        }
    } else {                                     // ---- transpose W ----
        int b2 = bid - 2048;
        int n0 = (b2 % 96) * 64, k0 = (b2 / 96) * 64;
        int r = t >> 2, c4 = t & 3;
#pragma unroll
        for (int j = 0; j < 4; ++j) {
            int c = (c4 + j * 4) * 4;
            fl4 v = *(const fl4*)&W[(size_t)(k0 + r) * N3 + n0 + c];
            Ts[r * 68 + c + 0] = f2bf(v.x);
            Ts[r * 68 + c + 1] = f2bf(v.y);
            Ts[r * 68 + c + 2] = f2bf(v.z);
            Ts[r * 68 + c + 3] = f2bf(v.w);
        }
        __syncthreads();
#pragma unroll
        for (int j = 0; j < 2; ++j) {
            int chunk = c4 + j * 4;
#pragma unroll
            for (int h = 0; h < 2; ++h) {
                us4 o;
                o.x = Ts[(chunk * 8 + h * 4 + 0) * 68 + r];
                o.y = Ts[(chunk * 8 + h * 4 + 1) * 68 + r];
                o.z = Ts[(chunk * 8 + h * 4 + 2) * 68 + r];
                o.w = Ts[(chunk * 8 + h * 4 + 3) * 68 + r];
                *(us4*)&Wt[(size_t)(n0 + r) * KDIM + k0 + chunk * 8 + h * 4] = o;
            }
        }
    }
}

// ---------------- QKV GEMM: C[4096][6144] = Xb * Wt^T ----------------
// BM=BN=256, BK=32, ring-4 LDS (4 x 32KB), 8 waves 2Mx4N (per-wave 128x64).
// Per K-tile: 2 phases {ds_read frags || stage tile t+3 -> s_barrier ->
// setprio MFMA x16 -> s_barrier}; vmcnt(8) once per K-tile (3 tiles in
// flight). Ring safety: stage of t+3 hits buf[(t-1)&3], last read before
// iter t-1's closing barrier. LDS: 2-m-packed 128B rows, slot^mr swizzle
// (paper-verified conflict-free: each ds_read_b128 = 8 words/bank exactly).
__global__ __launch_bounds__(512, 2) void k_gemm_qkv(const unsigned short* __restrict__ Xb,
                                                     const unsigned short* __restrict__ Wt,
                                                     unsigned short* __restrict__ Qb,
                                                     unsigned short* __restrict__ Kb,
                                                     unsigned short* __restrict__ Vt) {
    __shared__ alignas(16) char smem[131072];    // ring 4x(A16K+B16K); epilogue 2x64K
    int t = threadIdx.x;
    int wid = t >> 6, lane = t & 63, g = lane >> 4, l15 = lane & 15;
    int bid = blockIdx.x;
    bid = (bid & 7) * 48 + (bid >> 3);           // bijective XCD swizzle (384%8==0)
    int tmi = bid & 15, tni = bid >> 4;          // 16 M-tiles x 24 N-tiles
    int tm = tmi * 256, tn = tni * 256;
    const unsigned short* Abase = Xb + (size_t)tm * KDIM;
    const unsigned short* Bbase = Wt + (size_t)tn * KDIM;
    int wm = wid >> 2, wn = wid & 3;             // 2 M-waves x 4 N-waves
    f32x4 acc[8][4];
#pragma unroll
    for (int i = 0; i < 8; ++i)
#pragma unroll
        for (int j = 0; j < 4; ++j) acc[i][j] = (f32x4){0.f, 0.f, 0.f, 0.f};

    // LDS layout per ring slot: packed pairs of m-rows -> 128B LDS rows:
    // logical (m, k-chunk gk): mr=m>>1, slot=(m&1)*4+gk, stored at
    // mr*128 + ((slot^(mr&7))<<4). DMA dest linear; source pre-swizzled.
    auto stage_a = [&](int tile) {
        int k0 = tile * 32;
        char* dst = smem + (tile & 3) * 32768;
#pragma unroll
        for (int j = 0; j < 2; ++j) {
            int p = j * 8192 + t * 16;
            int s = p >> 4;
            int mr = s >> 3;
            int sl = (s & 7) ^ (mr & 7);
            int m = mr * 2 + (sl >> 2);
            gload16(Abase + (size_t)m * KDIM + k0 + (sl & 3) * 8,
                    dst + j * 8192 + wid * 1024);
        }
    };
    auto stage_b = [&](int tile) {
        int k0 = tile * 32;
        char* dst = smem + (tile & 3) * 32768 + 16384;
#pragma unroll
        for (int j = 0; j < 2; ++j) {
            int p = j * 8192 + t * 16;
            int s = p >> 4;
            int nr = s >> 3;
            int sl = (s & 7) ^ (nr & 7);
            int n = nr * 2 + (sl >> 2);
            gload16(Bbase + (size_t)n * KDIM + k0 + (sl & 3) * 8,
                    dst + j * 8192 + wid * 1024);
        }
    };

    // Prologue: prime 3 tiles, land tile 0 (12 issued, keep 8 in flight).
    stage_a(0); stage_b(0); stage_a(1); stage_b(1); stage_a(2); stage_b(2);
    asm volatile("s_waitcnt vmcnt(8)" ::: "memory");
    __builtin_amdgcn_s_barrier();
    asm volatile("" ::: "memory");

    auto iter = [&](int tt, int pf, int vm) {
        const char* Abuf = smem + (tt & 3) * 32768;
        const char* Bbuf = Abuf + 16384;
        bf16x8 bfv[4];
#pragma unroll
        for (int mh = 0; mh < 2; ++mh) {
            bf16x8 af[4];
#pragma unroll
            for (int q = 0; q < 4; ++q) {
                int ra = wm * 128 + mh * 64 + q * 16 + l15;
                int mr = ra >> 1;
                af[q] = *(const bf16x8*)(Abuf + mr * 128 +
                        ((((ra & 1) * 4 + g) ^ (mr & 7)) << 4));
            }
            if (mh == 0) {
#pragma unroll
                for (int bj = 0; bj < 4; ++bj) {
                    int rb = wn * 64 + bj * 16 + l15;
                    int nr = rb >> 1;
                    bfv[bj] = *(const bf16x8*)(Bbuf + nr * 128 +
                              ((((rb & 1) * 4 + g) ^ (nr & 7)) << 4));
                }
                if (pf >= 0) stage_a(pf);
            } else {
                if (pf >= 0) stage_b(pf);
            }
            asm volatile("" ::: "memory");
            __builtin_amdgcn_s_barrier();
            __builtin_amdgcn_s_setprio(1);
#pragma unroll
            for (int q = 0; q < 4; ++q)
#pragma unroll
                for (int bj = 0; bj < 4; ++bj)
                    acc[mh * 4 + q][bj] = __builtin_amdgcn_mfma_f32_16x16x32_bf16(
                        af[q], bfv[bj], acc[mh * 4 + q][bj], 0, 0, 0);
            __builtin_amdgcn_s_setprio(0);
            asm volatile("" ::: "memory");
            if (mh == 1) {                        // once per K-tile, counted
                if (vm == 8)      asm volatile("s_waitcnt vmcnt(8)" ::: "memory");
                else if (vm == 4) asm volatile("s_waitcnt vmcnt(4)" ::: "memory");
                else if (vm == 0) asm volatile("s_waitcnt vmcnt(0)" ::: "memory");
            }
            __builtin_amdgcn_s_barrier();
            asm volatile("" ::: "memory");
        }
    };

    for (int tt = 0; tt < 61; ++tt) iter(tt, tt + 3, 8);
    iter(61, -1, 4);
    iter(62, -1, 0);
    iter(63, -1, -1);

    // ---- Epilogue: regs -> LDS (two 64KB halves) -> coalesced global ----
    int b = tm >> 11, lp0 = tm & 2047;
    const float qsc = 0.08838834764831845f * 1.44269504089f;  // 1/sqrt(128)*log2e
    int half_w = wn >> 1;                        // wave's 128-col half
    int tyw = (tni * 2 + half_w) % 3;
    char* Tw = smem + half_w * 65536;
#pragma unroll
    for (int fi = 0; fi < 8; ++fi)
#pragma unroll
        for (int bj = 0; bj < 4; ++bj) {
            int d = wn * 64 + bj * 16 + l15;
            int dl = d & 127;
#pragma unroll
            for (int r = 0; r < 4; ++r) {
                int mm = wm * 128 + fi * 16 + g * 4 + r;
                float v = acc[fi][bj][r];
                unsigned short bv = f2bf(tyw == 0 ? v * qsc : v);
                int byte;
                if (tyw == 2)   // V: T[dl][mm], 128 rows x 512B
                    byte = dl * 512 + ((((mm >> 3) ^ (dl & 31)) & 31) << 4) + (mm & 7) * 2;
                else            // Q/K: T[mm][dl], 256 rows x 256B
                    byte = mm * 256 + ((((dl >> 3) ^ (mm & 15)) & 15) << 4) + (dl & 7) * 2;
                *(unsigned short*)(Tw + byte) = bv;
            }
        }
    __syncthreads();
#pragma unroll
    for (int half = 0; half < 2; ++half) {
        int ty = (tni * 2 + half) % 3;
        int h  = (tni * 2 + half) / 3;
        const char* Tr = smem + half * 65536;
        if (ty == 2) {
#pragma unroll
            for (int c = 0; c < 8; ++c) {
                int id = c * 512 + t;
                int dl = id >> 5, Lc = id & 31;
                bf16x8 vv = *(const bf16x8*)(Tr + dl * 512 + (((Lc ^ (dl & 31)) & 31) << 4));
                int kt = (lp0 >> 6) + (Lc >> 3);
                *(bf16x8*)&Vt[(size_t)((b * NHEAD + h) * 32 + kt) * 8192 + dl * 64 +
                              (Lc & 7) * 8] = vv;
            }
        } else {
            unsigned short* dst = (ty == 0) ? Qb : Kb;
#pragma unroll
            for (int c = 0; c < 8; ++c) {
                int id = c * 512 + t;
                int mm = id >> 4, cc = id & 15;
                bf16x8 vv = *(const bf16x8*)(Tr + mm * 256 + (((cc ^ (mm & 15)) & 15) << 4));
                *(bf16x8*)&dst[((size_t)(b * NHEAD + h) * SEQL + lp0 + mm) * 128 + cc * 8] = vv;
            }
        }
    }
}

// ---------------- Flash attention (causal), 32x32 swapped-QK^T ----------------
__global__ __launch_bounds__(256) void k_attn(const unsigned short* __restrict__ Qb,
                                              const unsigned short* __restrict__ Kb,
                                              const unsigned short* __restrict__ Vt,
                                              float* __restrict__ out) {
    __shared__ alignas(16) unsigned short Ks[64 * 128];   // 16KB, swz row&15
    __shared__ alignas(16) unsigned short Vs[128 * 64];   // 16KB, swz row&7
    __shared__ float Fx[4][32];
    int t = threadIdx.x, w = t >> 6, lane = t & 63;
    int l31 = lane & 31, hi = lane >> 5;
    int qi = 15 - (int)blockIdx.x;               // heavy tiles first
    int bh = blockIdx.y;
    int qb = qi * 128;
    int qg = qb + w * 32 + l31;
    int qwmin = qb + w * 32, qwmax = qwmin + 31;

    bf16x8 qf[8];
    const unsigned short* Qp = Qb + (size_t)(bh * SEQL + qg) * 128;
#pragma unroll
    for (int ks = 0; ks < 8; ++ks)
        qf[ks] = *(const bf16x8*)(Qp + ks * 16 + hi * 8);

    f32x16 accO[4];
#pragma unroll
    for (int db = 0; db < 4; ++db)
#pragma unroll
        for (int e = 0; e < 16; ++e) accO[db][e] = 0.f;
    float mstate = -3.0e38f, lsum = 0.f;

    int nkv = 2 * qi + 2;
    for (int kt = 0; kt < nkv; ++kt) {
        int kv0 = kt * 64;
#pragma unroll
        for (int j = 0; j < 4; ++j) {
            int p = j * 4096 + t * 16;
            int rk = p >> 8;
            int sk = ((p >> 4) & 15) ^ (rk & 15);
            gload16(Kb + (size_t)(bh * SEQL + kv0 + rk) * 128 + sk * 8,
                    (char*)Ks + j * 4096 + w * 1024);
            int rv = p >> 7;
            int sv = ((p >> 4) & 7) ^ (rv & 7);
            gload16(Vt + ((size_t)(bh * 32 + (kv0 >> 6)) * 128 + rv) * 64 + sv * 8,
                    (char*)Vs + j * 4096 + w * 1024);
        }
        __syncthreads();

        if (kv0 <= qwmax) {
            f32x16 s[2];
#pragma unroll
            for (int blk = 0; blk < 2; ++blk)
#pragma unroll
                for (int e = 0; e < 16; ++e) s[blk][e] = 0.f;
#pragma unroll
            for (int ks = 0; ks < 8; ++ks) {
                int c = ks * 2 + hi;
#pragma unroll
                for (int blk = 0; blk < 2; ++blk) {
                    int row = blk * 32 + l31;
                    bf16x8 kf = *(const bf16x8*)((const char*)Ks + row * 256 +
                                                 (((c ^ (row & 15)) & 15) << 4));
                    s[blk] = __builtin_amdgcn_mfma_f32_32x32x16_bf16(kf, qf[ks], s[blk], 0, 0, 0);
                }
            }
            if (kv0 + 63 > qwmin) {
#pragma unroll
                for (int blk = 0; blk < 2; ++blk)
#pragma unroll
                    for (int r = 0; r < 16; ++r) {
                        int kvg = kv0 + blk * 32 + (r & 3) + 8 * (r >> 2) + 4 * hi;
                        if (kvg > qg) s[blk][r] = -3.0e38f;
                    }
            }
            float tmax = -3.0e38f;
#pragma unroll
            for (int blk = 0; blk < 2; ++blk)
#pragma unroll
                for (int r = 0; r < 16; ++r) tmax = fmaxf(tmax, s[blk][r]);
            tmax = fmaxf(tmax, __shfl_xor(tmax, 32));
            if (__any(tmax > mstate + 8.0f)) {
                float mnew = fmaxf(mstate, tmax);
                float fs = __builtin_amdgcn_exp2f(mstate - mnew);
                lsum *= fs;
                mstate = mnew;
                Fx[w][l31] = fs;
                f32x4 fv[4];
#pragma unroll
                for (int q4 = 0; q4 < 4; ++q4)
                    fv[q4] = *(const f32x4*)&Fx[w][q4 * 8 + 4 * hi];
#pragma unroll
                for (int db = 0; db < 4; ++db)
#pragma unroll
                    for (int r = 0; r < 16; ++r)
                        accO[db][r] *= fv[r >> 2][r & 3];
            }
            float ps = 0.f;
#pragma unroll
            for (int blk = 0; blk < 2; ++blk)
#pragma unroll
                for (int r = 0; r < 16; ++r) {
                    float p = __builtin_amdgcn_exp2f(s[blk][r] - mstate);
                    s[blk][r] = p;
                    ps += p;
                }
            ps += __shfl_xor(ps, 32);
            lsum += ps;
            unsigned pa[4][4];
#pragma unroll
            for (int blk = 0; blk < 2; ++blk)
#pragma unroll
                for (int hf = 0; hf < 2; ++hf) {
                    int o = hf * 8;
                    unsigned d0 = cvtpk_bf16(s[blk][o + 0], s[blk][o + 1]);
                    unsigned d2 = cvtpk_bf16(s[blk][o + 4], s[blk][o + 5]);
                    plane32_swap(d0, d2);
                    unsigned d1 = cvtpk_bf16(s[blk][o + 2], s[blk][o + 3]);
                    unsigned d3 = cvtpk_bf16(s[blk][o + 6], s[blk][o + 7]);
                    plane32_swap(d1, d3);
                    pa[blk * 2 + hf][0] = d0; pa[blk * 2 + hf][1] = d1;
                    pa[blk * 2 + hf][2] = d2; pa[blk * 2 + hf][3] = d3;
                }
#pragma unroll
            for (int ksv = 0; ksv < 4; ++ksv) {
                u32x4 pu = {pa[ksv][0], pa[ksv][1], pa[ksv][2], pa[ksv][3]};
                bf16x8 paf = __builtin_bit_cast(bf16x8, pu);
                int c = ksv * 2 + hi;
#pragma unroll
                for (int db = 0; db < 4; ++db) {
                    int rv = db * 32 + l31;
                    bf16x8 vf = *(const bf16x8*)((const char*)Vs + rv * 128 +
                                                 (((c ^ (rv & 7)) & 7) << 4));
                    accO[db] = __builtin_amdgcn_mfma_f32_32x32x16_bf16(paf, vf, accO[db], 0, 0, 0);
                }
            }
        }
        __syncthreads();
    }
    float inv = 1.0f / lsum;
    Fx[w][l31] = inv;
    f32x4 iv[4];
#pragma unroll
    for (int q4 = 0; q4 < 4; ++q4)
        iv[q4] = *(const f32x4*)&Fx[w][q4 * 8 + 4 * hi];
    int b = bh >> 4, h = bh & 15;
    float* ob = out + (size_t)(b * SEQL + qb + w * 32) * 2048 + h * 128;
#pragma unroll
    for (int db = 0; db < 4; ++db)
#pragma unroll
        for (int r = 0; r < 16; ++r) {
            int qr = (r & 3) + 8 * (r >> 2) + 4 * hi;
            ob[(size_t)qr * 2048 + db * 32 + l31] = accO[db][r] * iv[r >> 2][r & 3];
        }
}

extern "C" void kernel_launch(void* const* d_in, const int* in_sizes, int n_in,
                              void* d_out, int out_size, void* d_ws, size_t ws_size,
                              hipStream_t stream) {
    const float* x = (const float*)d_in[0];
    const float* w = (const float*)d_in[2];
    float* out = (float*)d_out;
    char* ws = (char*)d_ws;
    unsigned short* Xb = (unsigned short*)(ws);                 // 16 MB [4096][2048]
    unsigned short* Wt = (unsigned short*)(ws + 16777216);      // 24 MB [6144][2048]
    unsigned short* Qb = (unsigned short*)(ws + 41943040);      // 16 MB [32][2048][128]
    unsigned short* Kb = (unsigned short*)(ws + 58720256);      // 16 MB [32][2048][128]
    unsigned short* Vt = (unsigned short*)(ws + 75497472);      // 16 MB [32][32][128][64]

    hipLaunchKernelGGL(k_prep, dim3(5120), dim3(256), 0, stream, x, w, Xb, Wt);
    hipLaunchKernelGGL(k_gemm_qkv, dim3(384), dim3(512), 0, stream, Xb, Wt, Qb, Kb, Vt);
    hipLaunchKernelGGL(k_attn, dim3(16, 32), dim3(256), 0, stream, Qb, Kb, Vt, out);
}

// Round 8
// 362.589 us; speedup vs baseline: 1.0020x; 1.0020x over previous
//
#include <hip/hip_runtime.h>

// Problem constants: B=2, L=2048, D=2048, H=16, DH=128
#define SEQL 2048
#define NHEAD 16
#define N3 6144      // 3*D
#define KDIM 2048    // D

typedef __attribute__((ext_vector_type(8))) short bf16x8;
typedef __attribute__((ext_vector_type(4))) float f32x4;
typedef __attribute__((ext_vector_type(16))) float f32x16;
typedef __attribute__((ext_vector_type(4))) unsigned short us4;
typedef __attribute__((ext_vector_type(4))) float fl4;
typedef __attribute__((ext_vector_type(4))) unsigned int u32x4;

__device__ __forceinline__ unsigned short f2bf(float x) {
    unsigned u = __builtin_bit_cast(unsigned, x);
    u += 0x7fffu + ((u >> 16) & 1u);            // RNE (inputs are finite)
    return (unsigned short)(u >> 16);
}

__device__ __forceinline__ void gload16(const void* g, void* l) {
    __builtin_amdgcn_global_load_lds(
        (const __attribute__((address_space(1))) unsigned int*)g,
        (__attribute__((address_space(3))) unsigned int*)l,
        16, 0, 0);
}

__device__ __forceinline__ unsigned cvtpk_bf16(float lo, float hi) {
    unsigned r;
    asm("v_cvt_pk_bf16_f32 %0, %1, %2" : "=v"(r) : "v"(lo), "v"(hi));
    return r;
}
__device__ __forceinline__ void plane32_swap(unsigned &a, unsigned &b) {
    asm("v_permlane32_swap_b32 %0, %1" : "+v"(a), "+v"(b));
}

// ---------------- Fused prep: X fp32->bf16  +  W [K][N]->Wt [N][K] bf16 ------
__global__ __launch_bounds__(256) void k_prep(const float* __restrict__ X,
                                              const float* __restrict__ W,
                                              unsigned short* __restrict__ Xb,
                                              unsigned short* __restrict__ Wt) {
    __shared__ alignas(16) unsigned short Ts[64 * 68];
    int bid = blockIdx.x, t = threadIdx.x;
    if (bid < 2048) {                            // ---- convert X ----
        int tid = bid * 256 + t;
        const fl4* in4 = (const fl4*)X;
        us4* out4 = (us4*)Xb;
#pragma unroll
        for (int j = 0; j < 4; ++j) {
            int idx = tid + j * 524288;
            fl4 v = in4[idx];
            us4 o;
            o.x = f2bf(v.x); o.y = f2bf(v.y); o.z = f2bf(v.z); o.w = f2bf(v.w);
            out4[idx] = o;
        }
    } else {                                     // ---- transpose W ----
        int b2 = bid - 2048;
        int n0 = (b2 % 96) * 64, k0 = (b2 / 96) * 64;
        int r = t >> 2, c4 = t & 3;
#pragma unroll
        for (int j = 0; j < 4; ++j) {
            int c = (c4 + j * 4) * 4;
            fl4 v = *(const fl4*)&W[(size_t)(k0 + r) * N3 + n0 + c];
            Ts[r * 68 + c + 0] = f2bf(v.x);
            Ts[r * 68 + c + 1] = f2bf(v.y);
            Ts[r * 68 + c + 2] = f2bf(v.z);
            Ts[r * 68 + c + 3] = f2bf(v.w);
        }
        __syncthreads();
#pragma unroll
        for (int j = 0; j < 2; ++j) {
            int chunk = c4 + j * 4;
#pragma unroll
            for (int h = 0; h < 2; ++h) {
                us4 o;
                o.x = Ts[(chunk * 8 + h * 4 + 0) * 68 + r];
                o.y = Ts[(chunk * 8 + h * 4 + 1) * 68 + r];
                o.z = Ts[(chunk * 8 + h * 4 + 2) * 68 + r];
                o.w = Ts[(chunk * 8 + h * 4 + 3) * 68 + r];
                *(us4*)&Wt[(size_t)(n0 + r) * KDIM + k0 + chunk * 8 + h * 4] = o;
            }
        }
    }
}

// ---------------- QKV GEMM: C[4096][6144] = Xb * Wt^T ----------------
// BM=128, BN=256, BK=32, 8 waves 2Mx4N (per-wave 64x64), ring-2 LDS 48KB
// -> 2 blocks/CU (launch_bounds(512,4), acc=64 VGPR). Grid 768 = 32x24
// tiles, 512 resident slots, dynamic smoothing. Counted vmcnt(3) ring:
// stage(t+2) after compute barrier, 3 gloads/tile (A1+B2). Cross-block TLP
// + ring prefetch hide HBM/L2 latency. r7's proven swizzle formulas.
__global__ __launch_bounds__(512, 4) void k_gemm_qkv(const unsigned short* __restrict__ Xb,
                                                     const unsigned short* __restrict__ Wt,
                                                     unsigned short* __restrict__ Qb,
                                                     unsigned short* __restrict__ Kb,
                                                     unsigned short* __restrict__ Vt) {
    __shared__ alignas(16) char smem[65536];     // ring 2x24KB; epilogue 2x32KB
    int t = threadIdx.x;
    int wid = t >> 6, lane = t & 63, g = lane >> 4, l15 = lane & 15;
    int bid = blockIdx.x;
    bid = (bid & 7) * 96 + (bid >> 3);           // bijective XCD swizzle (768%8==0)
    int tmi = bid & 31, tni = bid >> 5;          // 32 M-tiles x 24 N-tiles
    int tm = tmi * 128, tn = tni * 256;
    const unsigned short* Abase = Xb + (size_t)tm * KDIM;
    const unsigned short* Bbase = Wt + (size_t)tn * KDIM;
    int wm = wid >> 2, wn = wid & 3;             // 2 M-waves x 4 N-waves

    // Per-thread staging sources (hoisted; only k0 varies per tile).
    // LDS rows pack 2 logical rows: row r, slot sl (16B): phys = sl^(r&7).
    int mrA = t >> 3, psA = t & 7;
    int slA = psA ^ (mrA & 7);
    const unsigned short* a_src = Abase + (size_t)(mrA * 2 + (slA >> 2)) * KDIM + (slA & 3) * 8;
    int nr0 = t >> 3, sl0 = (t & 7) ^ (nr0 & 7);
    const unsigned short* b_src0 = Bbase + (size_t)(nr0 * 2 + (sl0 >> 2)) * KDIM + (sl0 & 3) * 8;
    int nr1 = 64 + (t >> 3), sl1 = (t & 7) ^ (nr1 & 7);
    const unsigned short* b_src1 = Bbase + (size_t)(nr1 * 2 + (sl1 >> 2)) * KDIM + (sl1 & 3) * 8;
    int awoff = wid * 1024 + lane * 16;

    // Per-lane fragment read offsets (lane-const).
    int offA[4], offB[4];
#pragma unroll
    for (int q = 0; q < 4; ++q) {
        int ra = wm * 64 + q * 16 + l15;
        int mr = ra >> 1;
        offA[q] = mr * 128 + ((((ra & 1) * 4 + g) ^ (mr & 7)) << 4);
        int rb = wn * 64 + q * 16 + l15;
        int nr = rb >> 1;
        offB[q] = nr * 128 + ((((rb & 1) * 4 + g) ^ (nr & 7)) << 4);
    }

    f32x4 acc[4][4];
#pragma unroll
    for (int i = 0; i < 4; ++i)
#pragma unroll
        for (int j = 0; j < 4; ++j) acc[i][j] = (f32x4){0.f, 0.f, 0.f, 0.f};

    auto STAGE = [&](int tile) {                 // 3 gloads, 24KB
        int k0 = tile * 32;
        char* base = smem + (tile & 1) * 24576;
        gload16(a_src + k0, base + awoff);
        gload16(b_src0 + k0, base + 8192 + awoff);
        gload16(b_src1 + k0, base + 16384 + awoff);
    };

    STAGE(0); STAGE(1);                          // 6 outstanding
    asm volatile("s_waitcnt vmcnt(3)" ::: "memory");   // tile 0 landed
    __builtin_amdgcn_s_barrier();
    asm volatile("" ::: "memory");

    for (int tt = 0; tt < 64; ++tt) {
        const char* base = smem + (tt & 1) * 24576;
        bf16x8 af[4], bfv[4];
#pragma unroll
        for (int q = 0; q < 4; ++q) {
            af[q]  = *(const bf16x8*)(base + offA[q]);
            bfv[q] = *(const bf16x8*)(base + 8192 + offB[q]);
        }
        __builtin_amdgcn_s_setprio(1);
#pragma unroll
        for (int i = 0; i < 4; ++i)
#pragma unroll
            for (int j = 0; j < 4; ++j)
                acc[i][j] = __builtin_amdgcn_mfma_f32_16x16x32_bf16(
                    af[i], bfv[j], acc[i][j], 0, 0, 0);
        __builtin_amdgcn_s_setprio(0);
        asm volatile("" ::: "memory");
        __builtin_amdgcn_s_barrier();            // all waves done reading buf[tt&1]
        asm volatile("" ::: "memory");
        if (tt < 62) {
            STAGE(tt + 2);                       // overwrite buf[tt&1]
            asm volatile("s_waitcnt vmcnt(3)" ::: "memory");   // tile tt+1 landed
        } else if (tt == 62) {
            asm volatile("s_waitcnt vmcnt(0)" ::: "memory");   // tile 63 landed
        }
        __builtin_amdgcn_s_barrier();
        asm volatile("" ::: "memory");
    }

    // ---- Epilogue: regs -> LDS (two 32KB transpose halves) -> global ----
    int b = tm >> 11, lp0 = tm & 2047;
    const float qsc = 0.08838834764831845f * 1.44269504089f;  // 1/sqrt(128)*log2e
    int half_w = wn >> 1;                        // wave's 128-col half
    int tyw = (2 * tni + half_w) % 3;
    char* Tw = smem + half_w * 32768;
#pragma unroll
    for (int fi = 0; fi < 4; ++fi)
#pragma unroll
        for (int bj = 0; bj < 4; ++bj) {
            int dl = (wn & 1) * 64 + bj * 16 + l15;   // 0..127 within half
#pragma unroll
            for (int r = 0; r < 4; ++r) {
                int mm = wm * 64 + fi * 16 + g * 4 + r;
                float v = acc[fi][bj][r];
                unsigned short bv = f2bf(tyw == 0 ? v * qsc : v);
                int byte;
                if (tyw == 2)   // V: T[dl][mm], 128 rows x 256B
                    byte = dl * 256 + ((((mm >> 3) ^ (dl & 15)) & 15) << 4) + (mm & 7) * 2;
                else            // Q/K: T[mm][dl], 128 rows x 256B
                    byte = mm * 256 + ((((dl >> 3) ^ (mm & 15)) & 15) << 4) + (dl & 7) * 2;
                *(unsigned short*)(Tw + byte) = bv;
            }
        }
    __syncthreads();
#pragma unroll
    for (int half = 0; half < 2; ++half) {
        int ty = (2 * tni + half) % 3;
        int hh = (tni * 256 + half * 128) / 384;
        const char* Tr = smem + half * 32768;
        if (ty == 2) {
#pragma unroll
            for (int i = 0; i < 4; ++i) {
                int id = i * 512 + t;
                int dv = id >> 4, c2 = id & 15;
                bf16x8 vv = *(const bf16x8*)(Tr + dv * 256 + (((c2 ^ (dv & 15)) & 15) << 4));
                int kt = (lp0 >> 6) + (c2 >> 3);
                *(bf16x8*)&Vt[(size_t)((b * NHEAD + hh) * 32 + kt) * 8192 + dv * 64 +
                              (c2 & 7) * 8] = vv;
            }
        } else {
            unsigned short* dst = (ty == 0) ? Qb : Kb;
#pragma unroll
            for (int i = 0; i < 4; ++i) {
                int id = i * 512 + t;
                int mm = id >> 4, cc = id & 15;
                bf16x8 vv = *(const bf16x8*)(Tr + mm * 256 + (((cc ^ (mm & 15)) & 15) << 4));
                *(bf16x8*)&dst[((size_t)(b * NHEAD + hh) * SEQL + lp0 + mm) * 128 + cc * 8] = vv;
            }
        }
    }
}

// ---------------- Flash attention (causal), 32x32 swapped-QK^T ----------------
__global__ __launch_bounds__(256) void k_attn(const unsigned short* __restrict__ Qb,
                                              const unsigned short* __restrict__ Kb,
                                              const unsigned short* __restrict__ Vt,
                                              float* __restrict__ out) {
    __shared__ alignas(16) unsigned short Ks[64 * 128];   // 16KB, swz row&15
    __shared__ alignas(16) unsigned short Vs[128 * 64];   // 16KB, swz row&7
    __shared__ float Fx[4][32];
    int t = threadIdx.x, w = t >> 6, lane = t & 63;
    int l31 = lane & 31, hi = lane >> 5;
    int qi = 15 - (int)blockIdx.x;               // heavy tiles first
    int bh = blockIdx.y;
    int qb = qi * 128;
    int qg = qb + w * 32 + l31;
    int qwmin = qb + w * 32, qwmax = qwmin + 31;

    bf16x8 qf[8];
    const unsigned short* Qp = Qb + (size_t)(bh * SEQL + qg) * 128;
#pragma unroll
    for (int ks = 0; ks < 8; ++ks)
        qf[ks] = *(const bf16x8*)(Qp + ks * 16 + hi * 8);

    f32x16 accO[4];
#pragma unroll
    for (int db = 0; db < 4; ++db)
#pragma unroll
        for (int e = 0; e < 16; ++e) accO[db][e] = 0.f;
    float mstate = -3.0e38f, lsum = 0.f;

    int nkv = 2 * qi + 2;
    for (int kt = 0; kt < nkv; ++kt) {
        int kv0 = kt * 64;
#pragma unroll
        for (int j = 0; j < 4; ++j) {
            int p = j * 4096 + t * 16;
            int rk = p >> 8;
            int sk = ((p >> 4) & 15) ^ (rk & 15);
            gload16(Kb + (size_t)(bh * SEQL + kv0 + rk) * 128 + sk * 8,
                    (char*)Ks + j * 4096 + w * 1024);
            int rv = p >> 7;
            int sv = ((p >> 4) & 7) ^ (rv & 7);
            gload16(Vt + ((size_t)(bh * 32 + (kv0 >> 6)) * 128 + rv) * 64 + sv * 8,
                    (char*)Vs + j * 4096 + w * 1024);
        }
        __syncthreads();

        if (kv0 <= qwmax) {
            f32x16 s[2];
#pragma unroll
            for (int blk = 0; blk < 2; ++blk)
#pragma unroll
                for (int e = 0; e < 16; ++e) s[blk][e] = 0.f;
#pragma unroll
            for (int ks = 0; ks < 8; ++ks) {
                int c = ks * 2 + hi;
#pragma unroll
                for (int blk = 0; blk < 2; ++blk) {
                    int row = blk * 32 + l31;
                    bf16x8 kf = *(const bf16x8*)((const char*)Ks + row * 256 +
                                                 (((c ^ (row & 15)) & 15) << 4));
                    s[blk] = __builtin_amdgcn_mfma_f32_32x32x16_bf16(kf, qf[ks], s[blk], 0, 0, 0);
                }
            }
            if (kv0 + 63 > qwmin) {
#pragma unroll
                for (int blk = 0; blk < 2; ++blk)
#pragma unroll
                    for (int r = 0; r < 16; ++r) {
                        int kvg = kv0 + blk * 32 + (r & 3) + 8 * (r >> 2) + 4 * hi;
                        if (kvg > qg) s[blk][r] = -3.0e38f;
                    }
            }
            float tmax = -3.0e38f;
#pragma unroll
            for (int blk = 0; blk < 2; ++blk)
#pragma unroll
                for (int r = 0; r < 16; ++r) tmax = fmaxf(tmax, s[blk][r]);
            tmax = fmaxf(tmax, __shfl_xor(tmax, 32));
            if (__any(tmax > mstate + 8.0f)) {
                float mnew = fmaxf(mstate, tmax);
                float fs = __builtin_amdgcn_exp2f(mstate - mnew);
                lsum *= fs;
                mstate = mnew;
                Fx[w][l31] = fs;
                f32x4 fv[4];
#pragma unroll
                for (int q4 = 0; q4 < 4; ++q4)
                    fv[q4] = *(const f32x4*)&Fx[w][q4 * 8 + 4 * hi];
#pragma unroll
                for (int db = 0; db < 4; ++db)
#pragma unroll
                    for (int r = 0; r < 16; ++r)
                        accO[db][r] *= fv[r >> 2][r & 3];
            }
            float ps = 0.f;
#pragma unroll
            for (int blk = 0; blk < 2; ++blk)
#pragma unroll
                for (int r = 0; r < 16; ++r) {
                    float p = __builtin_amdgcn_exp2f(s[blk][r] - mstate);
                    s[blk][r] = p;
                    ps += p;
                }
            ps += __shfl_xor(ps, 32);
            lsum += ps;
            unsigned pa[4][4];
#pragma unroll
            for (int blk = 0; blk < 2; ++blk)
#pragma unroll
                for (int hf = 0; hf < 2; ++hf) {
                    int o = hf * 8;
                    unsigned d0 = cvtpk_bf16(s[blk][o + 0], s[blk][o + 1]);
                    unsigned d2 = cvtpk_bf16(s[blk][o + 4], s[blk][o + 5]);
                    plane32_swap(d0, d2);
                    unsigned d1 = cvtpk_bf16(s[blk][o + 2], s[blk][o + 3]);
                    unsigned d3 = cvtpk_bf16(s[blk][o + 6], s[blk][o + 7]);
                    plane32_swap(d1, d3);
                    pa[blk * 2 + hf][0] = d0; pa[blk * 2 + hf][1] = d1;
                    pa[blk * 2 + hf][2] = d2; pa[blk * 2 + hf][3] = d3;
                }
#pragma unroll
            for (int ksv = 0; ksv < 4; ++ksv) {
                u32x4 pu = {pa[ksv][0], pa[ksv][1], pa[ksv][2], pa[ksv][3]};
                bf16x8 paf = __builtin_bit_cast(bf16x8, pu);
                int c = ksv * 2 + hi;
#pragma unroll
                for (int db = 0; db < 4; ++db) {
                    int rv = db * 32 + l31;
                    bf16x8 vf = *(const bf16x8*)((const char*)Vs + rv * 128 +
                                                 (((c ^ (rv & 7)) & 7) << 4));
                    accO[db] = __builtin_amdgcn_mfma_f32_32x32x16_bf16(paf, vf, accO[db], 0, 0, 0);
                }
            }
        }
        __syncthreads();
    }
    float inv = 1.0f / lsum;
    Fx[w][l31] = inv;
    f32x4 iv[4];
#pragma unroll
    for (int q4 = 0; q4 < 4; ++q4)
        iv[q4] = *(const f32x4*)&Fx[w][q4 * 8 + 4 * hi];
    int b = bh >> 4, h = bh & 15;
    float* ob = out + (size_t)(b * SEQL + qb + w * 32) * 2048 + h * 128;
#pragma unroll
    for (int db = 0; db < 4; ++db)
#pragma unroll
        for (int r = 0; r < 16; ++r) {
            int qr = (r & 3) + 8 * (r >> 2) + 4 * hi;
            ob[(size_t)qr * 2048 + db * 32 + l31] = accO[db][r] * iv[r >> 2][r & 3];
        }
}

extern "C" void kernel_launch(void* const* d_in, const int* in_sizes, int n_in,
                              void* d_out, int out_size, void* d_ws, size_t ws_size,
                              hipStream_t stream) {
    const float* x = (const float*)d_in[0];
    const float* w = (const float*)d_in[2];
    float* out = (float*)d_out;
    char* ws = (char*)d_ws;
    unsigned short* Xb = (unsigned short*)(ws);                 // 16 MB [4096][2048]
    unsigned short* Wt = (unsigned short*)(ws + 16777216);      // 24 MB [6144][2048]
    unsigned short* Qb = (unsigned short*)(ws + 41943040);      // 16 MB [32][2048][128]
    unsigned short* Kb = (unsigned short*)(ws + 58720256);      // 16 MB [32][2048][128]
    unsigned short* Vt = (unsigned short*)(ws + 75497472);      // 16 MB [32][32][128][64]

    hipLaunchKernelGGL(k_prep, dim3(5120), dim3(256), 0, stream, x, w, Xb, Wt);
    hipLaunchKernelGGL(k_gemm_qkv, dim3(768), dim3(512), 0, stream, Xb, Wt, Qb, Kb, Vt);
    hipLaunchKernelGGL(k_attn, dim3(16, 32), dim3(256), 0, stream, Qb, Kb, Vt, out);
}

// Round 10
// 342.373 us; speedup vs baseline: 1.0611x; 1.0590x over previous
//
#include <hip/hip_runtime.h>

// Problem constants: B=2, L=2048, D=2048, H=16, DH=128
#define SEQL 2048
#define NHEAD 16
#define N3 6144      // 3*D
#define KDIM 2048    // D

typedef __attribute__((ext_vector_type(8))) short bf16x8;
typedef __attribute__((ext_vector_type(8))) unsigned short us8;
typedef __attribute__((ext_vector_type(4))) float f32x4;
typedef __attribute__((ext_vector_type(16))) float f32x16;
typedef __attribute__((ext_vector_type(4))) unsigned short us4;
typedef __attribute__((ext_vector_type(4))) float fl4;
typedef __attribute__((ext_vector_type(4))) unsigned int u32x4;

__device__ __forceinline__ unsigned short f2bf(float x) {
    unsigned u = __builtin_bit_cast(unsigned, x);
    u += 0x7fffu + ((u >> 16) & 1u);            // RNE (inputs are finite)
    return (unsigned short)(u >> 16);
}

__device__ __forceinline__ void gload16(const void* g, void* l) {
    __builtin_amdgcn_global_load_lds(
        (const __attribute__((address_space(1))) unsigned int*)g,
        (__attribute__((address_space(3))) unsigned int*)l,
        16, 0, 0);
}

__device__ __forceinline__ unsigned cvtpk_bf16(float lo, float hi) {
    unsigned r;
    asm("v_cvt_pk_bf16_f32 %0, %1, %2" : "=v"(r) : "v"(lo), "v"(hi));
    return r;
}
__device__ __forceinline__ void plane32_swap(unsigned &a, unsigned &b) {
    asm("v_permlane32_swap_b32 %0, %1" : "+v"(a), "+v"(b));
}

// ---------------- Fused prep: X fp32->bf16  +  W [K][N]->Wt [N][K] bf16 ------
__global__ __launch_bounds__(256) void k_prep(const float* __restrict__ X,
                                              const float* __restrict__ W,
                                              unsigned short* __restrict__ Xb,
                                              unsigned short* __restrict__ Wt) {
    __shared__ alignas(16) unsigned short Ts[64 * 68];
    int bid = blockIdx.x, t = threadIdx.x;
    if (bid < 2048) {                            // ---- convert X ----
        int tid = bid * 256 + t;
        const fl4* in4 = (const fl4*)X;
        us4* out4 = (us4*)Xb;
#pragma unroll
        for (int j = 0; j < 4; ++j) {
            int idx = tid + j * 524288;
            fl4 v = in4[idx];
            us4 o;
            o.x = f2bf(v.x); o.y = f2bf(v.y); o.z = f2bf(v.z); o.w = f2bf(v.w);
            out4[idx] = o;
        }
    } else {                                     // ---- transpose W ----
        int b2 = bid - 2048;
        int n0 = (b2 % 96) * 64, k0 = (b2 / 96) * 64;
        int r = t >> 2, c4 = t & 3;
#pragma unroll
        for (int j = 0; j < 4; ++j) {
            int c = (c4 + j * 4) * 4;
            fl4 v = *(const fl4*)&W[(size_t)(k0 + r) * N3 + n0 + c];
            Ts[r * 68 + c + 0] = f2bf(v.x);
            Ts[r * 68 + c + 1] = f2bf(v.y);
            Ts[r * 68 + c + 2] = f2bf(v.z);
            Ts[r * 68 + c + 3] = f2bf(v.w);
        }
        __syncthreads();
#pragma unroll
        for (int j = 0; j < 2; ++j) {
            int chunk = c4 * 2 + j;              // 0..7, 16B contiguous store
            us8 o;
#pragma unroll
            for (int e = 0; e < 8; ++e)
                o[e] = Ts[(chunk * 8 + e) * 68 + r];
            *(us8*)&Wt[(size_t)(n0 + r) * KDIM + k0 + chunk * 8] = o;
        }
    }
}

// ---------------- QKV GEMM: C[4096][6144] = Xb * Wt^T ----------------
// (unchanged from r8 — proven: BM=128,BN=256,BK=32, ring-2 48KB, vmcnt(3))
__global__ __launch_bounds__(512, 4) void k_gemm_qkv(const unsigned short* __restrict__ Xb,
                                                     const unsigned short* __restrict__ Wt,
                                                     unsigned short* __restrict__ Qb,
                                                     unsigned short* __restrict__ Kb,
                                                     unsigned short* __restrict__ Vt) {
    __shared__ alignas(16) char smem[65536];     // ring 2x24KB; epilogue 2x32KB
    int t = threadIdx.x;
    int wid = t >> 6, lane = t & 63, g = lane >> 4, l15 = lane & 15;
    int bid = blockIdx.x;
    bid = (bid & 7) * 96 + (bid >> 3);           // bijective XCD swizzle (768%8==0)
    int tmi = bid & 31, tni = bid >> 5;          // 32 M-tiles x 24 N-tiles
    int tm = tmi * 128, tn = tni * 256;
    const unsigned short* Abase = Xb + (size_t)tm * KDIM;
    const unsigned short* Bbase = Wt + (size_t)tn * KDIM;
    int wm = wid >> 2, wn = wid & 3;             // 2 M-waves x 4 N-waves

    int mrA = t >> 3, psA = t & 7;
    int slA = psA ^ (mrA & 7);
    const unsigned short* a_src = Abase + (size_t)(mrA * 2 + (slA >> 2)) * KDIM + (slA & 3) * 8;
    int nr0 = t >> 3, sl0 = (t & 7) ^ (nr0 & 7);
    const unsigned short* b_src0 = Bbase + (size_t)(nr0 * 2 + (sl0 >> 2)) * KDIM + (sl0 & 3) * 8;
    int nr1 = 64 + (t >> 3), sl1 = (t & 7) ^ (nr1 & 7);
    const unsigned short* b_src1 = Bbase + (size_t)(nr1 * 2 + (sl1 >> 2)) * KDIM + (sl1 & 3) * 8;
    int awoff = wid * 1024 + lane * 16;

    int offA[4], offB[4];
#pragma unroll
    for (int q = 0; q < 4; ++q) {
        int ra = wm * 64 + q * 16 + l15;
        int mr = ra >> 1;
        offA[q] = mr * 128 + ((((ra & 1) * 4 + g) ^ (mr & 7)) << 4);
        int rb = wn * 64 + q * 16 + l15;
        int nr = rb >> 1;
        offB[q] = nr * 128 + ((((rb & 1) * 4 + g) ^ (nr & 7)) << 4);
    }

    f32x4 acc[4][4];
#pragma unroll
    for (int i = 0; i < 4; ++i)
#pragma unroll
        for (int j = 0; j < 4; ++j) acc[i][j] = (f32x4){0.f, 0.f, 0.f, 0.f};

    auto STAGE = [&](int tile) {                 // 3 gloads, 24KB
        int k0 = tile * 32;
        char* base = smem + (tile & 1) * 24576;
        gload16(a_src + k0, base + awoff);
        gload16(b_src0 + k0, base + 8192 + awoff);
        gload16(b_src1 + k0, base + 16384 + awoff);
    };

    STAGE(0); STAGE(1);
    asm volatile("s_waitcnt vmcnt(3)" ::: "memory");
    __builtin_amdgcn_s_barrier();
    asm volatile("" ::: "memory");

    for (int tt = 0; tt < 64; ++tt) {
        const char* base = smem + (tt & 1) * 24576;
        bf16x8 af[4], bfv[4];
#pragma unroll
        for (int q = 0; q < 4; ++q) {
            af[q]  = *(const bf16x8*)(base + offA[q]);
            bfv[q] = *(const bf16x8*)(base + 8192 + offB[q]);
        }
        __builtin_amdgcn_s_setprio(1);
#pragma unroll
        for (int i = 0; i < 4; ++i)
#pragma unroll
            for (int j = 0; j < 4; ++j)
                acc[i][j] = __builtin_amdgcn_mfma_f32_16x16x32_bf16(
                    af[i], bfv[j], acc[i][j], 0, 0, 0);
        __builtin_amdgcn_s_setprio(0);
        asm volatile("" ::: "memory");
        __builtin_amdgcn_s_barrier();
        asm volatile("" ::: "memory");
        if (tt < 62) {
            STAGE(tt + 2);
            asm volatile("s_waitcnt vmcnt(3)" ::: "memory");
        } else if (tt == 62) {
            asm volatile("s_waitcnt vmcnt(0)" ::: "memory");
        }
        __builtin_amdgcn_s_barrier();
        asm volatile("" ::: "memory");
    }

    // ---- Epilogue (unchanged r8) ----
    int b = tm >> 11, lp0 = tm & 2047;
    const float qsc = 0.08838834764831845f * 1.44269504089f;
    int half_w = wn >> 1;
    int tyw = (2 * tni + half_w) % 3;
    char* Tw = smem + half_w * 32768;
#pragma unroll
    for (int fi = 0; fi < 4; ++fi)
#pragma unroll
        for (int bj = 0; bj < 4; ++bj) {
            int dl = (wn & 1) * 64 + bj * 16 + l15;
#pragma unroll
            for (int r = 0; r < 4; ++r) {
                int mm = wm * 64 + fi * 16 + g * 4 + r;
                float v = acc[fi][bj][r];
                unsigned short bv = f2bf(tyw == 0 ? v * qsc : v);
                int byte;
                if (tyw == 2)
                    byte = dl * 256 + ((((mm >> 3) ^ (dl & 15)) & 15) << 4) + (mm & 7) * 2;
                else
                    byte = mm * 256 + ((((dl >> 3) ^ (mm & 15)) & 15) << 4) + (dl & 7) * 2;
                *(unsigned short*)(Tw + byte) = bv;
            }
        }
    __syncthreads();
#pragma unroll
    for (int half = 0; half < 2; ++half) {
        int ty = (2 * tni + half) % 3;
        int hh = (tni * 256 + half * 128) / 384;
        const char* Tr = smem + half * 32768;
        if (ty == 2) {
#pragma unroll
            for (int i = 0; i < 4; ++i) {
                int id = i * 512 + t;
                int dv = id >> 4, c2 = id & 15;
                bf16x8 vv = *(const bf16x8*)(Tr + dv * 256 + (((c2 ^ (dv & 15)) & 15) << 4));
                int kt = (lp0 >> 6) + (c2 >> 3);
                *(bf16x8*)&Vt[(size_t)((b * NHEAD + hh) * 32 + kt) * 8192 + dv * 64 +
                              (c2 & 7) * 8] = vv;
            }
        } else {
            unsigned short* dst = (ty == 0) ? Qb : Kb;
#pragma unroll
            for (int i = 0; i < 4; ++i) {
                int id = i * 512 + t;
                int mm = id >> 4, cc = id & 15;
                bf16x8 vv = *(const bf16x8*)(Tr + mm * 256 + (((cc ^ (mm & 15)) & 15) << 4));
                *(bf16x8*)&dst[((size_t)(b * NHEAD + hh) * SEQL + lp0 + mm) * 128 + cc * 8] = vv;
            }
        }
    }
}

// ---------------- Flash attention (causal), balanced paired q-tiles ----------
// 2 warps/block, q-tile 64 (warp=32 q-rows), KV tile 64. Block processes
// q-tile qa=31-p then qb=p sequentially -> EXACTLY 33 kv-iters per block
// (perfect balance; r8's 123us was same-qi blocks stacking on one CU).
// 33KB LDS -> 4 blocks/CU = 8 waves/CU = 2 waves/SIMD (cross-block overlap
// hides staging drain). bh XCD-chunked: 16 blocks sharing a bh's KV (1MB)
// land on one XCD -> 4MB = L2-resident.
__global__ __launch_bounds__(128, 2) void k_attn(const unsigned short* __restrict__ Qb,
                                                 const unsigned short* __restrict__ Kb,
                                                 const unsigned short* __restrict__ Vt,
                                                 float* __restrict__ out) {
    __shared__ alignas(16) unsigned short Ks[64 * 128];   // 16KB, swz row&15
    __shared__ alignas(16) unsigned short Vs[128 * 64];   // 16KB, swz row&7
    __shared__ float Fx[2][32];
    int t = threadIdx.x, w = t >> 6, lane = t & 63;
    int l31 = lane & 31, hi = lane >> 5;
    int pid = blockIdx.x;                        // 512 = 16 pairs x 32 bh
    int xcd = pid & 7, q3 = pid >> 3;
    int bh = (q3 >> 4) * 8 + xcd;                // XCD-chunked bh
    int pr = q3 & 15;
    int qa = 31 - pr, qb2 = pr;                  // 64-row q-tile indices
    int n1 = qa + 1;                             // kv tiles for qa; total 33

    int qt = qa;
    int qg = qt * 64 + w * 32 + l31;
    int qwmin = qt * 64 + w * 32, qwmax = qwmin + 31;

    bf16x8 qf[8];
    {
        const unsigned short* Qp = Qb + (size_t)(bh * SEQL + qg) * 128;
#pragma unroll
        for (int ks = 0; ks < 8; ++ks)
            qf[ks] = *(const bf16x8*)(Qp + ks * 16 + hi * 8);
    }

    f32x16 accO[4];
#pragma unroll
    for (int db = 0; db < 4; ++db)
#pragma unroll
        for (int e = 0; e < 16; ++e) accO[db][e] = 0.f;
    float mstate = -3.0e38f, lsum = 0.f;
    int b_out = bh >> 4, h_out = bh & 15;

    auto writeO = [&](int qtv) {
        float inv = 1.0f / lsum;
        Fx[w][l31] = inv;
        f32x4 iv[4];
#pragma unroll
        for (int q4 = 0; q4 < 4; ++q4)
            iv[q4] = *(const f32x4*)&Fx[w][q4 * 8 + 4 * hi];
        float* ob = out + (size_t)(b_out * SEQL + qtv * 64 + w * 32) * 2048 + h_out * 128;
#pragma unroll
        for (int db = 0; db < 4; ++db)
#pragma unroll
            for (int r = 0; r < 16; ++r) {
                int qr = (r & 3) + 8 * (r >> 2) + 4 * hi;
                ob[(size_t)qr * 2048 + db * 32 + l31] = accO[db][r] * iv[r >> 2][r & 3];
            }
    };

    for (int it = 0; it < 33; ++it) {
        int kv0 = (it < n1 ? it : it - n1) * 64;
        // ---- stage K/V tile (single buffer; 8+8 gloads per thread) ----
#pragma unroll
        for (int j = 0; j < 8; ++j) {
            int p = j * 2048 + t * 16;
            int rk = p >> 8;
            int sk = ((p >> 4) & 15) ^ (rk & 15);
            gload16(Kb + (size_t)(bh * SEQL + kv0 + rk) * 128 + sk * 8,
                    (char*)Ks + j * 2048 + w * 1024);
            int rv = p >> 7;
            int sv = ((p >> 4) & 7) ^ (rv & 7);
            gload16(Vt + ((size_t)(bh * 32 + (kv0 >> 6)) * 128 + rv) * 64 + sv * 8,
                    (char*)Vs + j * 2048 + w * 1024);
        }
        __syncthreads();

        if (it == n1) {                          // segment switch (block-uniform)
            writeO(qa);
            qt = qb2;
            qg = qt * 64 + w * 32 + l31;
            qwmin = qt * 64 + w * 32; qwmax = qwmin + 31;
            const unsigned short* Qp = Qb + (size_t)(bh * SEQL + qg) * 128;
#pragma unroll
            for (int ks = 0; ks < 8; ++ks)
                qf[ks] = *(const bf16x8*)(Qp + ks * 16 + hi * 8);
#pragma unroll
            for (int db = 0; db < 4; ++db)
#pragma unroll
                for (int e = 0; e < 16; ++e) accO[db][e] = 0.f;
            mstate = -3.0e38f; lsum = 0.f;
        }

        if (kv0 <= qwmax) {                      // wave-uniform gate
            f32x16 s[2];
#pragma unroll
            for (int blk = 0; blk < 2; ++blk)
#pragma unroll
                for (int e = 0; e < 16; ++e) s[blk][e] = 0.f;
#pragma unroll
            for (int ks = 0; ks < 8; ++ks) {
                int c = ks * 2 + hi;
#pragma unroll
                for (int blk = 0; blk < 2; ++blk) {
                    int row = blk * 32 + l31;
                    bf16x8 kf = *(const bf16x8*)((const char*)Ks + row * 256 +
                                                 (((c ^ (row & 15)) & 15) << 4));
                    s[blk] = __builtin_amdgcn_mfma_f32_32x32x16_bf16(kf, qf[ks], s[blk], 0, 0, 0);
                }
            }
            if (kv0 + 63 > qwmin) {              // diagonal: apply causal mask
#pragma unroll
                for (int blk = 0; blk < 2; ++blk)
#pragma unroll
                    for (int r = 0; r < 16; ++r) {
                        int kvg = kv0 + blk * 32 + (r & 3) + 8 * (r >> 2) + 4 * hi;
                        if (kvg > qg) s[blk][r] = -3.0e38f;
                    }
            }
            float tmax = -3.0e38f;
#pragma unroll
            for (int blk = 0; blk < 2; ++blk)
#pragma unroll
                for (int r = 0; r < 16; ++r) tmax = fmaxf(tmax, s[blk][r]);
            tmax = fmaxf(tmax, __shfl_xor(tmax, 32));
            if (__any(tmax > mstate + 8.0f)) {   // defer-max (T13)
                float mnew = fmaxf(mstate, tmax);
                float fs = __builtin_amdgcn_exp2f(mstate - mnew);
                lsum *= fs;
                mstate = mnew;
                Fx[w][l31] = fs;
                f32x4 fv[4];
#pragma unroll
                for (int q4 = 0; q4 < 4; ++q4)
                    fv[q4] = *(const f32x4*)&Fx[w][q4 * 8 + 4 * hi];
#pragma unroll
                for (int db = 0; db < 4; ++db)
#pragma unroll
                    for (int r = 0; r < 16; ++r)
                        accO[db][r] *= fv[r >> 2][r & 3];
            }
            float ps = 0.f;
#pragma unroll
            for (int blk = 0; blk < 2; ++blk)
#pragma unroll
                for (int r = 0; r < 16; ++r) {
                    float p = __builtin_amdgcn_exp2f(s[blk][r] - mstate);
                    s[blk][r] = p;
                    ps += p;
                }
            ps += __shfl_xor(ps, 32);
            lsum += ps;
            unsigned pa[4][4];
#pragma unroll
            for (int blk = 0; blk < 2; ++blk)
#pragma unroll
                for (int hf = 0; hf < 2; ++hf) {
                    int o = hf * 8;
                    unsigned d0 = cvtpk_bf16(s[blk][o + 0], s[blk][o + 1]);
                    unsigned d2 = cvtpk_bf16(s[blk][o + 4], s[blk][o + 5]);
                    plane32_swap(d0, d2);
                    unsigned d1 = cvtpk_bf16(s[blk][o + 2], s[blk][o + 3]);
                    unsigned d3 = cvtpk_bf16(s[blk][o + 6], s[blk][o + 7]);
                    plane32_swap(d1, d3);
                    pa[blk * 2 + hf][0] = d0; pa[blk * 2 + hf][1] = d1;
                    pa[blk * 2 + hf][2] = d2; pa[blk * 2 + hf][3] = d3;
                }
#pragma unroll
            for (int ksv = 0; ksv < 4; ++ksv) {
                u32x4 pu = {pa[ksv][0], pa[ksv][1], pa[ksv][2], pa[ksv][3]};
                bf16x8 paf = __builtin_bit_cast(bf16x8, pu);
                int c = ksv * 2 + hi;
#pragma unroll
                for (int db = 0; db < 4; ++db) {
                    int rv = db * 32 + l31;
                    bf16x8 vf = *(const bf16x8*)((const char*)Vs + rv * 128 +
                                                 (((c ^ (rv & 7)) & 7) << 4));
                    accO[db] = __builtin_amdgcn_mfma_f32_32x32x16_bf16(paf, vf, accO[db], 0, 0, 0);
                }
            }
        }
        __syncthreads();
    }
    writeO(qb2);
}

extern "C" void kernel_launch(void* const* d_in, const int* in_sizes, int n_in,
                              void* d_out, int out_size, void* d_ws, size_t ws_size,
                              hipStream_t stream) {
    const float* x = (const float*)d_in[0];
    const float* w = (const float*)d_in[2];
    float* out = (float*)d_out;
    char* ws = (char*)d_ws;
    unsigned short* Xb = (unsigned short*)(ws);                 // 16 MB [4096][2048]
    unsigned short* Wt = (unsigned short*)(ws + 16777216);      // 24 MB [6144][2048]
    unsigned short* Qb = (unsigned short*)(ws + 41943040);      // 16 MB [32][2048][128]
    unsigned short* Kb = (unsigned short*)(ws + 58720256);      // 16 MB [32][2048][128]
    unsigned short* Vt = (unsigned short*)(ws + 75497472);      // 16 MB [32][32][128][64]

    hipLaunchKernelGGL(k_prep, dim3(5120), dim3(256), 0, stream, x, w, Xb, Wt);
    hipLaunchKernelGGL(k_gemm_qkv, dim3(768), dim3(512), 0, stream, Xb, Wt, Qb, Kb, Vt);
    hipLaunchKernelGGL(k_attn, dim3(512), dim3(128), 0, stream, Qb, Kb, Vt, out);
}